// Round 2
// baseline (1431.228 us; speedup 1.0000x reference)
//
#include <hip/hip_runtime.h>
#include <math.h>
#include <stdint.h>

// Problem constants
constexpr int B   = 8;
constexpr int DIM = 128;
constexpr int S   = 1024;
constexpr int CF  = 512;
constexpr int K   = 16384;
constexpr float INV_TAU = 5.0f;    // 1/0.2
constexpr float EPSF    = 1e-12f;

// Output layout (flat, in return order): output_g [B,1+K], target_g [B],
// output_d [B,1+K,S], target_d [B,S]
constexpr int64_t OG_OFF = 0;
constexpr int64_t TG_OFF = (int64_t)B * (K + 1);                 // 131080
constexpr int64_t OD_OFF = TG_OFF + B;                           // 131088
constexpr int64_t TD_OFF = OD_OFF + (int64_t)B * (K + 1) * S;    // 134357008

typedef __attribute__((ext_vector_type(8))) short s16x8;   // 8 bf16 (4 VGPRs)
typedef __attribute__((ext_vector_type(4))) float f32x4;   // MFMA accumulator

// Split fp32 into bf16 hi + bf16 lo (truncation; combined repr err ~2^-14 rel)
__device__ inline void split2(float x, uint16_t& h, uint16_t& l) {
    uint32_t bx = __float_as_uint(x);
    h = (uint16_t)(bx >> 16);
    float r = x - __uint_as_float(bx & 0xFFFF0000u);
    l = (uint16_t)(__float_as_uint(r) >> 16);
}

// ---------------------------------------------------------------------------
// Zero the int32 target outputs (bit pattern 0 is valid as both f32 and i32)
__global__ void zero_targets_kernel(float* out) {
    int t = blockIdx.x * 256 + threadIdx.x;
    if (t < B) out[TG_OFF + t] = 0.0f;
    if (t < B * S) out[TD_OFF + t] = 0.0f;
}

// ---------------------------------------------------------------------------
// Normalize g_q, g_k (axis=1, D=128); emit g_qn, g_kn and pos_g logits.
__global__ void g_norm_kernel(const float* __restrict__ g_q,
                              const float* __restrict__ g_k,
                              float* __restrict__ g_qn,
                              float* __restrict__ g_kn,
                              float* __restrict__ out) {
    int b = blockIdx.x;
    int d = threadIdx.x;  // 0..127
    float q = g_q[b * DIM + d];
    float k = g_k[b * DIM + d];
    float sq = q * q, sk = k * k;
#pragma unroll
    for (int off = 32; off > 0; off >>= 1) {
        sq += __shfl_down(sq, off, 64);
        sk += __shfl_down(sk, off, 64);
    }
    __shared__ float red[4];
    int w = d >> 6;
    if ((d & 63) == 0) { red[w] = sq; red[2 + w] = sk; }
    __syncthreads();
    float invq = 1.0f / fmaxf(sqrtf(red[0] + red[1]), EPSF);
    float invk = 1.0f / fmaxf(sqrtf(red[2] + red[3]), EPSF);
    float qn = q * invq, kn = k * invk;
    g_qn[b * DIM + d] = qn;
    g_kn[b * DIM + d] = kn;
    float p = qn * kn;
#pragma unroll
    for (int off = 32; off > 0; off >>= 1) p += __shfl_down(p, off, 64);
    __shared__ float red2[2];
    if ((d & 63) == 0) red2[w] = p;
    __syncthreads();
    if (d == 0) out[OG_OFF + (int64_t)b * (K + 1)] = (red2[0] + red2[1]) * INV_TAU;
}

// ---------------------------------------------------------------------------
// neg_g: out[b, 1+k] = (g_qn[b,:] . queue_g[:,k]) / TAU.
__global__ void neg_g_kernel(const float* __restrict__ g_qn,
                             const float* __restrict__ queue_g,
                             float* __restrict__ out) {
    __shared__ float gq[B * DIM];
    int t = threadIdx.x;
    for (int i = t; i < B * DIM; i += 256) gq[i] = g_qn[i];
    __syncthreads();
    int k = blockIdx.x * 256 + t;
    float acc[B] = {0, 0, 0, 0, 0, 0, 0, 0};
    for (int d = 0; d < DIM; ++d) {
        float v = queue_g[(int64_t)d * K + k];
#pragma unroll
        for (int b = 0; b < B; ++b) acc[b] = fmaf(gq[b * DIM + d], v, acc[b]);
    }
#pragma unroll
    for (int b = 0; b < B; ++b)
        out[OG_OFF + (int64_t)b * (K + 1) + 1 + k] = acc[b] * INV_TAU;
}

// ---------------------------------------------------------------------------
// Inverse L2 norms along the channel axis of x[B,ROWS,S] -> rn[B,S].
template <int ROWS>
__global__ void invnorm_kernel(const float* __restrict__ x, float* __restrict__ rn) {
    int b = blockIdx.y;
    int s = blockIdx.x * 64 + (threadIdx.x & 63);
    int g = threadIdx.x >> 6;
    const float* base = x + (int64_t)b * ROWS * S + s;
    float acc = 0.0f;
    for (int r = g; r < ROWS; r += 4) {
        float v = base[(int64_t)r * S];
        acc = fmaf(v, v, acc);
    }
    __shared__ float red[256];
    red[threadIdx.x] = acc;
    __syncthreads();
    if (g == 0) {
        int sl = threadIdx.x;
        float tot = red[sl] + red[64 + sl] + red[128 + sl] + red[192 + sl];
        rn[b * S + s] = 1.0f / fmaxf(sqrtf(tot), EPSF);
    }
}

// ---------------------------------------------------------------------------
// cosine argmax (unchanged this round)
constexpr int CC = 32;
__global__ void cos_argmax_kernel(const float* __restrict__ f_k,
                                  const float* __restrict__ f_q,
                                  const float* __restrict__ rn_fk,
                                  const float* __restrict__ rn_fq,
                                  float* __restrict__ pmax,
                                  int* __restrict__ pidx) {
    int jt = blockIdx.x, ic = blockIdx.y, b = blockIdx.z;
    int j0 = jt * 64;
    int tx = threadIdx.x & 15, ty = threadIdx.x >> 4;
    __shared__ __align__(16) float sk[CC][68];
    __shared__ __align__(16) float sq[CC][68];
    const float* fkb = f_k + (int64_t)b * CF * S;
    const float* fqb = f_q + (int64_t)b * CF * S;

    float bestv[4];
    int besti[4];
#pragma unroll
    for (int jj = 0; jj < 4; ++jj) { bestv[jj] = -INFINITY; besti[jj] = 0; }
    float rq[4];
#pragma unroll
    for (int jj = 0; jj < 4; ++jj) rq[jj] = rn_fq[b * S + j0 + ty * 4 + jj];

    for (int it = 0; it < 4; ++it) {
        int i_base = ic * 256 + it * 64;
        float acc[4][4] = {};
        for (int c0 = 0; c0 < CF; c0 += CC) {
            for (int e = threadIdx.x; e < CC * 64; e += 256) {
                int r = e >> 6, col = e & 63;
                sk[r][col] = fkb[(int64_t)(c0 + r) * S + i_base + col];
                sq[r][col] = fqb[(int64_t)(c0 + r) * S + j0 + col];
            }
            __syncthreads();
#pragma unroll
            for (int r = 0; r < CC; ++r) {
                float4 av4 = *(const float4*)&sk[r][tx * 4];
                float4 bv4 = *(const float4*)&sq[r][ty * 4];
                float a_[4] = {av4.x, av4.y, av4.z, av4.w};
                float b_[4] = {bv4.x, bv4.y, bv4.z, bv4.w};
#pragma unroll
                for (int ii = 0; ii < 4; ++ii)
#pragma unroll
                    for (int jj = 0; jj < 4; ++jj)
                        acc[ii][jj] = fmaf(a_[ii], b_[jj], acc[ii][jj]);
            }
            __syncthreads();
        }
        float rk[4];
#pragma unroll
        for (int ii = 0; ii < 4; ++ii) rk[ii] = rn_fk[b * S + i_base + tx * 4 + ii];
#pragma unroll
        for (int jj = 0; jj < 4; ++jj)
#pragma unroll
            for (int ii = 0; ii < 4; ++ii) {
                float v = acc[ii][jj] * rk[ii] * rq[jj];
                if (v > bestv[jj]) { bestv[jj] = v; besti[jj] = i_base + tx * 4 + ii; }
            }
    }
#pragma unroll
    for (int jj = 0; jj < 4; ++jj) {
        float v = bestv[jj];
        int idx = besti[jj];
#pragma unroll
        for (int off = 8; off > 0; off >>= 1) {
            float ov = __shfl_down(v, off, 16);
            int oi = __shfl_down(idx, off, 16);
            if (ov > v || (ov == v && oi < idx)) { v = ov; idx = oi; }
        }
        if (tx == 0) {
            int j = j0 + ty * 4 + jj;
            pmax[(int64_t)(ic * B + b) * S + j] = v;
            pidx[(int64_t)(ic * B + b) * S + j] = idx;
        }
    }
}

__global__ void argmax_merge_kernel(const float* __restrict__ pmax,
                                    const int* __restrict__ pidx,
                                    int* __restrict__ match) {
    int t = blockIdx.x * 256 + threadIdx.x;
    if (t >= B * S) return;
    int b = t / S, s = t % S;
    float bv = -INFINITY;
    int bi = 0;
    for (int ic = 0; ic < 4; ++ic) {
        float v = pmax[(int64_t)(ic * B + b) * S + s];
        int i = pidx[(int64_t)(ic * B + b) * S + s];
        if (v > bv || (v == bv && i < bi)) { bv = v; bi = i; }
    }
    match[t] = bi;
}

// ---------------------------------------------------------------------------
// queue_d f32 [DIM][K]  ->  qT_hi/qT_lo bf16 [K][DIM]  (transpose + hi/lo split)
__global__ void queue_split_kernel(const float* __restrict__ qd,
                                   uint16_t* __restrict__ qhi,
                                   uint16_t* __restrict__ qlo) {
    int q0 = blockIdx.x * 64;
    __shared__ float tile[DIM][65];
    for (int e = threadIdx.x; e < DIM * 64; e += 256) {
        int d = e >> 6, c = e & 63;
        tile[d][c] = qd[(int64_t)d * K + q0 + c];
    }
    __syncthreads();
    int qq = threadIdx.x >> 2;   // 0..63 (row within tile)
    int dg = threadIdx.x & 3;    // 0..3  (32 d each)
    uint16_t* gh = qhi + (int64_t)(q0 + qq) * DIM + dg * 32;
    uint16_t* gl = qlo + (int64_t)(q0 + qq) * DIM + dg * 32;
#pragma unroll
    for (int v = 0; v < 4; ++v) {
        uint32_t ph[4], pl[4];
#pragma unroll
        for (int p = 0; p < 4; ++p) {
            int d = dg * 32 + v * 8 + p * 2;
            uint16_t h0, l0, h1, l1;
            split2(tile[d][qq], h0, l0);
            split2(tile[d + 1][qq], h1, l1);
            ph[p] = (uint32_t)h0 | ((uint32_t)h1 << 16);
            pl[p] = (uint32_t)l0 | ((uint32_t)l1 << 16);
        }
        *(uint4*)(gh + v * 8) = make_uint4(ph[0], ph[1], ph[2], ph[3]);
        *(uint4*)(gl + v * 8) = make_uint4(pl[0], pl[1], pl[2], pl[3]);
    }
}

// ---------------------------------------------------------------------------
// Fused: gather d_q at match (normalized), emit transposed bf16 hi/lo
// d_qgT [b][z][DIM], and pos_d output (d_k norm fused).
__global__ void gather_prep_kernel(const float* __restrict__ d_q,
                                   const float* __restrict__ d_k,
                                   const float* __restrict__ rn_dq,
                                   const int* __restrict__ match,
                                   uint16_t* __restrict__ ghi,
                                   uint16_t* __restrict__ glo,
                                   float* __restrict__ out) {
    int b = blockIdx.y, z0 = blockIdx.x * 64;
    int zl = threadIdx.x & 63, dg = threadIdx.x >> 6;  // dg 0..3
    __shared__ float tile[DIM][65];
    __shared__ float redd[4][64], redn[4][64];
    __shared__ int   sm[64];
    __shared__ float ssc[64];
    if (threadIdx.x < 64) {
        int m = match[b * S + z0 + threadIdx.x];
        sm[threadIdx.x] = m;
        ssc[threadIdx.x] = rn_dq[b * S + m];
    }
    __syncthreads();
    int m = sm[zl];
    float sc = ssc[zl];
    const float* dqb = d_q + (int64_t)b * DIM * S;
    const float* dkb = d_k + (int64_t)b * DIM * S + z0;
    float dot = 0.0f, nk = 0.0f;
    for (int i = 0; i < 32; ++i) {
        int d = dg * 32 + i;
        float val = dqb[(int64_t)d * S + m] * sc;
        float kv  = dkb[(int64_t)d * S + zl];
        tile[d][zl] = val;
        dot = fmaf(kv, val, dot);
        nk  = fmaf(kv, kv, nk);
    }
    redd[dg][zl] = dot;
    redn[dg][zl] = nk;
    __syncthreads();
    if (dg == 0) {
        float D  = redd[0][zl] + redd[1][zl] + redd[2][zl] + redd[3][zl];
        float Nk = redn[0][zl] + redn[1][zl] + redn[2][zl] + redn[3][zl];
        out[OD_OFF + (int64_t)b * (K + 1) * S + z0 + zl] =
            D / fmaxf(sqrtf(Nk), EPSF) * INV_TAU;
    }
    // transposed split write: row z, 128 contiguous d
    int zz = threadIdx.x >> 2;   // 0..63
    int dg2 = threadIdx.x & 3;   // 0..3
    uint16_t* gh = ghi + ((int64_t)b * S + z0 + zz) * DIM + dg2 * 32;
    uint16_t* gl = glo + ((int64_t)b * S + z0 + zz) * DIM + dg2 * 32;
#pragma unroll
    for (int v = 0; v < 4; ++v) {
        uint32_t ph[4], pl[4];
#pragma unroll
        for (int p = 0; p < 4; ++p) {
            int d = dg2 * 32 + v * 8 + p * 2;
            uint16_t h0, l0, h1, l1;
            split2(tile[d][zz], h0, l0);
            split2(tile[d + 1][zz], h1, l1);
            ph[p] = (uint32_t)h0 | ((uint32_t)h1 << 16);
            pl[p] = (uint32_t)l0 | ((uint32_t)l1 << 16);
        }
        *(uint4*)(gh + v * 8) = make_uint4(ph[0], ph[1], ph[2], ph[3]);
        *(uint4*)(gl + v * 8) = make_uint4(pl[0], pl[1], pl[2], pl[3]);
    }
}

// ---------------------------------------------------------------------------
// neg_d via MFMA, bf16 hi/lo 3-pass split (AhBh + AhBl + AlBh), fp32 acc.
// C[q,z] = sum_d qT[q][d] * gT[b][z][d].
// 1-D grid of 8192 blocks, XCD-chunked swizzle: each XCD owns a contiguous
// 16-q-tile range (operand footprint/XCD: ~1MB qhi + 4.2MB ghi, L2-resident).
// Epilogue: per-wave LDS transpose -> float4 writes (256B/row, no RMW).
__global__ void neg_d_mfma_kernel(const uint16_t* __restrict__ qhi,
                                  const uint16_t* __restrict__ qlo,
                                  const uint16_t* __restrict__ ghi,
                                  const uint16_t* __restrict__ glo,
                                  float* __restrict__ out) {
    // dispatch id -> work id: XCD n (= d%8) gets work [n*1024, (n+1)*1024)
    int d_id = blockIdx.x;
    int work = (d_id & 7) * 1024 + (d_id >> 3);
    // work decode, (z-tile, b) fastest: x = q-tile [0,128)
    int x = work >> 6;
    int rem = work & 63;
    int y = rem & 7;     // z-tile [0,8)
    int b = rem >> 3;    // batch [0,8)

    int q0 = x * 128;
    int z0 = y * 128;
    int wave = threadIdx.x >> 6, lane = threadIdx.x & 63;
    int wq = q0 + (wave >> 1) * 64;      // wave's q origin
    int wz = z0 + (wave & 1) * 64;       // wave's z origin
    int r  = lane & 15;                  // A row / B col within 16
    int kd = (lane >> 4) * 8;            // k(d) offset within 32-chunk

    f32x4 acc[4][4];
    const f32x4 z4 = {0.0f, 0.0f, 0.0f, 0.0f};
#pragma unroll
    for (int i = 0; i < 4; ++i)
#pragma unroll
        for (int j = 0; j < 4; ++j) acc[i][j] = z4;

    const int64_t gbase = (int64_t)b * S;
#pragma unroll
    for (int ds = 0; ds < 4; ++ds) {
        int doff = ds * 32 + kd;
        s16x8 ah[4], al[4], bh[4], bl[4];
#pragma unroll
        for (int i = 0; i < 4; ++i) {
            int64_t arow = (int64_t)(wq + i * 16 + r) * DIM + doff;
            ah[i] = *(const s16x8*)(qhi + arow);
            al[i] = *(const s16x8*)(qlo + arow);
            int64_t brow = (gbase + wz + i * 16 + r) * DIM + doff;
            bh[i] = *(const s16x8*)(ghi + brow);
            bl[i] = *(const s16x8*)(glo + brow);
        }
        // pass 1: hi*hi
#pragma unroll
        for (int i = 0; i < 4; ++i)
#pragma unroll
            for (int j = 0; j < 4; ++j)
                acc[i][j] = __builtin_amdgcn_mfma_f32_16x16x32_bf16(ah[i], bh[j], acc[i][j], 0, 0, 0);
        // pass 2: hi*lo
#pragma unroll
        for (int i = 0; i < 4; ++i)
#pragma unroll
            for (int j = 0; j < 4; ++j)
                acc[i][j] = __builtin_amdgcn_mfma_f32_16x16x32_bf16(ah[i], bl[j], acc[i][j], 0, 0, 0);
        // pass 3: lo*hi
#pragma unroll
        for (int i = 0; i < 4; ++i)
#pragma unroll
            for (int j = 0; j < 4; ++j)
                acc[i][j] = __builtin_amdgcn_mfma_f32_16x16x32_bf16(al[i], bh[j], acc[i][j], 0, 0, 0);
    }

    // Epilogue: per-wave LDS transpose so global writes are float4 rows.
    // C/D layout (m89-verified): col = lane&15, row = (lane>>4)*4 + reg.
    __shared__ __align__(16) float st[4][16][68];
    int col = lane & 15;
    int rb  = (lane >> 4) * 4;
    int rr  = lane >> 4;           // read-phase row group 0..3
    int zc  = (lane & 15) * 4;     // read-phase z offset (float4)
#pragma unroll
    for (int i = 0; i < 4; ++i) {
#pragma unroll
        for (int j = 0; j < 4; ++j)
#pragma unroll
            for (int reg = 0; reg < 4; ++reg)
                st[wave][rb + reg][j * 16 + col] = acc[i][j][reg];
        __syncthreads();
#pragma unroll
        for (int pass = 0; pass < 4; ++pass) {
            int row = pass * 4 + rr;
            float4 v = *(const float4*)&st[wave][row][zc];
            v.x *= INV_TAU; v.y *= INV_TAU; v.z *= INV_TAU; v.w *= INV_TAU;
            int q = wq + i * 16 + row;
            *(float4*)&out[OD_OFF + ((int64_t)b * (K + 1) + 1 + q) * S + wz + zc] = v;
        }
        __syncthreads();
    }
}

// ---------------------------------------------------------------------------
extern "C" void kernel_launch(void* const* d_in, const int* in_sizes, int n_in,
                              void* d_out, int out_size, void* d_ws, size_t ws_size,
                              hipStream_t stream) {
    const float* g_q     = (const float*)d_in[0];
    const float* g_k     = (const float*)d_in[1];
    const float* d_q     = (const float*)d_in[2];
    const float* d_k     = (const float*)d_in[3];
    const float* feat_q  = (const float*)d_in[4];
    const float* feat_k  = (const float*)d_in[5];
    const float* queue_g = (const float*)d_in[6];
    const float* queue_d = (const float*)d_in[7];
    float* out = (float*)d_out;

    // Workspace carve: ~0.4 MB f32 scratch + 12.6 MB bf16 hi/lo operands
    float* ws    = (float*)d_ws;
    float* g_qn  = ws;               // 1024
    float* g_kn  = g_qn + 1024;      // 1024
    float* rn_fq = g_kn + 1024;      // 8192
    float* rn_fk = rn_fq + B * S;    // 8192
    float* rn_dq = rn_fk + B * S;    // 8192
    float* pmax  = rn_dq + B * S;    // 4*8192
    int*   pidx  = (int*)(pmax + 4 * B * S);  // 4*8192
    int*   match = pidx + 4 * B * S;          // 8192
    uint16_t* qhi = (uint16_t*)(match + B * S);   // [K][DIM] bf16
    uint16_t* qlo = qhi + (size_t)K * DIM;        // [K][DIM] bf16
    uint16_t* ghi = qlo + (size_t)K * DIM;        // [B][S][DIM] bf16
    uint16_t* glo = ghi + (size_t)B * S * DIM;    // [B][S][DIM] bf16

    zero_targets_kernel<<<(B * S + 255) / 256, 256, 0, stream>>>(out);
    g_norm_kernel<<<B, DIM, 0, stream>>>(g_q, g_k, g_qn, g_kn, out);
    neg_g_kernel<<<K / 256, 256, 0, stream>>>(g_qn, queue_g, out);
    queue_split_kernel<<<K / 64, 256, 0, stream>>>(queue_d, qhi, qlo);
    invnorm_kernel<CF><<<dim3(S / 64, B), 256, 0, stream>>>(feat_q, rn_fq);
    invnorm_kernel<CF><<<dim3(S / 64, B), 256, 0, stream>>>(feat_k, rn_fk);
    invnorm_kernel<DIM><<<dim3(S / 64, B), 256, 0, stream>>>(d_q, rn_dq);
    cos_argmax_kernel<<<dim3(S / 64, 4, B), 256, 0, stream>>>(feat_k, feat_q, rn_fk, rn_fq, pmax, pidx);
    argmax_merge_kernel<<<(B * S + 255) / 256, 256, 0, stream>>>(pmax, pidx, match);
    gather_prep_kernel<<<dim3(S / 64, B), 256, 0, stream>>>(d_q, d_k, rn_dq, match, ghi, glo, out);
    neg_d_mfma_kernel<<<8192, 256, 0, stream>>>(qhi, qlo, ghi, glo, out);
}

// Round 3
// 1354.246 us; speedup vs baseline: 1.0568x; 1.0568x over previous
//
#include <hip/hip_runtime.h>
#include <math.h>
#include <stdint.h>

// Problem constants
constexpr int B   = 8;
constexpr int DIM = 128;
constexpr int S   = 1024;
constexpr int CF  = 512;
constexpr int K   = 16384;
constexpr float INV_TAU = 5.0f;    // 1/0.2
constexpr float EPSF    = 1e-12f;

// Output layout (flat, in return order): output_g [B,1+K], target_g [B],
// output_d [B,1+K,S], target_d [B,S]
constexpr int64_t OG_OFF = 0;
constexpr int64_t TG_OFF = (int64_t)B * (K + 1);                 // 131080
constexpr int64_t OD_OFF = TG_OFF + B;                           // 131088
constexpr int64_t TD_OFF = OD_OFF + (int64_t)B * (K + 1) * S;    // 134357008

typedef __attribute__((ext_vector_type(8))) short s16x8;   // 8 bf16 (4 VGPRs)
typedef __attribute__((ext_vector_type(4))) float f32x4;   // MFMA accumulator

// Split fp32 into bf16 hi + bf16 lo (truncation; combined repr err ~2^-14 rel)
__device__ inline void split2(float x, uint16_t& h, uint16_t& l) {
    uint32_t bx = __float_as_uint(x);
    h = (uint16_t)(bx >> 16);
    float r = x - __uint_as_float(bx & 0xFFFF0000u);
    l = (uint16_t)(__float_as_uint(r) >> 16);
}

// ---------------------------------------------------------------------------
// Zero the int32 target outputs (bit pattern 0 is valid as both f32 and i32)
__global__ void zero_targets_kernel(float* out) {
    int t = blockIdx.x * 256 + threadIdx.x;
    if (t < B) out[TG_OFF + t] = 0.0f;
    if (t < B * S) out[TD_OFF + t] = 0.0f;
}

// ---------------------------------------------------------------------------
// Normalize g_q, g_k (axis=1, D=128); emit g_qn, g_kn and pos_g logits.
__global__ void g_norm_kernel(const float* __restrict__ g_q,
                              const float* __restrict__ g_k,
                              float* __restrict__ g_qn,
                              float* __restrict__ g_kn,
                              float* __restrict__ out) {
    int b = blockIdx.x;
    int d = threadIdx.x;  // 0..127
    float q = g_q[b * DIM + d];
    float k = g_k[b * DIM + d];
    float sq = q * q, sk = k * k;
#pragma unroll
    for (int off = 32; off > 0; off >>= 1) {
        sq += __shfl_down(sq, off, 64);
        sk += __shfl_down(sk, off, 64);
    }
    __shared__ float red[4];
    int w = d >> 6;
    if ((d & 63) == 0) { red[w] = sq; red[2 + w] = sk; }
    __syncthreads();
    float invq = 1.0f / fmaxf(sqrtf(red[0] + red[1]), EPSF);
    float invk = 1.0f / fmaxf(sqrtf(red[2] + red[3]), EPSF);
    float qn = q * invq, kn = k * invk;
    g_qn[b * DIM + d] = qn;
    g_kn[b * DIM + d] = kn;
    float p = qn * kn;
#pragma unroll
    for (int off = 32; off > 0; off >>= 1) p += __shfl_down(p, off, 64);
    __shared__ float red2[2];
    if ((d & 63) == 0) red2[w] = p;
    __syncthreads();
    if (d == 0) out[OG_OFF + (int64_t)b * (K + 1)] = (red2[0] + red2[1]) * INV_TAU;
}

// ---------------------------------------------------------------------------
// neg_g: out[b, 1+k] = (g_qn[b,:] . queue_g[:,k]) / TAU.
__global__ void neg_g_kernel(const float* __restrict__ g_qn,
                             const float* __restrict__ queue_g,
                             float* __restrict__ out) {
    __shared__ float gq[B * DIM];
    int t = threadIdx.x;
    for (int i = t; i < B * DIM; i += 256) gq[i] = g_qn[i];
    __syncthreads();
    int k = blockIdx.x * 256 + t;
    float acc[B] = {0, 0, 0, 0, 0, 0, 0, 0};
    for (int d = 0; d < DIM; ++d) {
        float v = queue_g[(int64_t)d * K + k];
#pragma unroll
        for (int b = 0; b < B; ++b) acc[b] = fmaf(gq[b * DIM + d], v, acc[b]);
    }
#pragma unroll
    for (int b = 0; b < B; ++b)
        out[OG_OFF + (int64_t)b * (K + 1) + 1 + k] = acc[b] * INV_TAU;
}

// ---------------------------------------------------------------------------
// Inverse L2 norms along the channel axis of x[B,ROWS,S] -> rn[B,S].
template <int ROWS>
__global__ void invnorm_kernel(const float* __restrict__ x, float* __restrict__ rn) {
    int b = blockIdx.y;
    int s = blockIdx.x * 64 + (threadIdx.x & 63);
    int g = threadIdx.x >> 6;
    const float* base = x + (int64_t)b * ROWS * S + s;
    float acc = 0.0f;
    for (int r = g; r < ROWS; r += 4) {
        float v = base[(int64_t)r * S];
        acc = fmaf(v, v, acc);
    }
    __shared__ float red[256];
    red[threadIdx.x] = acc;
    __syncthreads();
    if (g == 0) {
        int sl = threadIdx.x;
        float tot = red[sl] + red[64 + sl] + red[128 + sl] + red[192 + sl];
        rn[b * S + s] = 1.0f / fmaxf(sqrtf(tot), EPSF);
    }
}

// ---------------------------------------------------------------------------
// cosine argmax (unchanged this round)
constexpr int CC = 32;
__global__ void cos_argmax_kernel(const float* __restrict__ f_k,
                                  const float* __restrict__ f_q,
                                  const float* __restrict__ rn_fk,
                                  const float* __restrict__ rn_fq,
                                  float* __restrict__ pmax,
                                  int* __restrict__ pidx) {
    int jt = blockIdx.x, ic = blockIdx.y, b = blockIdx.z;
    int j0 = jt * 64;
    int tx = threadIdx.x & 15, ty = threadIdx.x >> 4;
    __shared__ __align__(16) float sk[CC][68];
    __shared__ __align__(16) float sq[CC][68];
    const float* fkb = f_k + (int64_t)b * CF * S;
    const float* fqb = f_q + (int64_t)b * CF * S;

    float bestv[4];
    int besti[4];
#pragma unroll
    for (int jj = 0; jj < 4; ++jj) { bestv[jj] = -INFINITY; besti[jj] = 0; }
    float rq[4];
#pragma unroll
    for (int jj = 0; jj < 4; ++jj) rq[jj] = rn_fq[b * S + j0 + ty * 4 + jj];

    for (int it = 0; it < 4; ++it) {
        int i_base = ic * 256 + it * 64;
        float acc[4][4] = {};
        for (int c0 = 0; c0 < CF; c0 += CC) {
            for (int e = threadIdx.x; e < CC * 64; e += 256) {
                int r = e >> 6, col = e & 63;
                sk[r][col] = fkb[(int64_t)(c0 + r) * S + i_base + col];
                sq[r][col] = fqb[(int64_t)(c0 + r) * S + j0 + col];
            }
            __syncthreads();
#pragma unroll
            for (int r = 0; r < CC; ++r) {
                float4 av4 = *(const float4*)&sk[r][tx * 4];
                float4 bv4 = *(const float4*)&sq[r][ty * 4];
                float a_[4] = {av4.x, av4.y, av4.z, av4.w};
                float b_[4] = {bv4.x, bv4.y, bv4.z, bv4.w};
#pragma unroll
                for (int ii = 0; ii < 4; ++ii)
#pragma unroll
                    for (int jj = 0; jj < 4; ++jj)
                        acc[ii][jj] = fmaf(a_[ii], b_[jj], acc[ii][jj]);
            }
            __syncthreads();
        }
        float rk[4];
#pragma unroll
        for (int ii = 0; ii < 4; ++ii) rk[ii] = rn_fk[b * S + i_base + tx * 4 + ii];
#pragma unroll
        for (int jj = 0; jj < 4; ++jj)
#pragma unroll
            for (int ii = 0; ii < 4; ++ii) {
                float v = acc[ii][jj] * rk[ii] * rq[jj];
                if (v > bestv[jj]) { bestv[jj] = v; besti[jj] = i_base + tx * 4 + ii; }
            }
    }
#pragma unroll
    for (int jj = 0; jj < 4; ++jj) {
        float v = bestv[jj];
        int idx = besti[jj];
#pragma unroll
        for (int off = 8; off > 0; off >>= 1) {
            float ov = __shfl_down(v, off, 16);
            int oi = __shfl_down(idx, off, 16);
            if (ov > v || (ov == v && oi < idx)) { v = ov; idx = oi; }
        }
        if (tx == 0) {
            int j = j0 + ty * 4 + jj;
            pmax[(int64_t)(ic * B + b) * S + j] = v;
            pidx[(int64_t)(ic * B + b) * S + j] = idx;
        }
    }
}

__global__ void argmax_merge_kernel(const float* __restrict__ pmax,
                                    const int* __restrict__ pidx,
                                    int* __restrict__ match) {
    int t = blockIdx.x * 256 + threadIdx.x;
    if (t >= B * S) return;
    int b = t / S, s = t % S;
    float bv = -INFINITY;
    int bi = 0;
    for (int ic = 0; ic < 4; ++ic) {
        float v = pmax[(int64_t)(ic * B + b) * S + s];
        int i = pidx[(int64_t)(ic * B + b) * S + s];
        if (v > bv || (v == bv && i < bi)) { bv = v; bi = i; }
    }
    match[t] = bi;
}

// ---------------------------------------------------------------------------
// queue_d f32 [DIM][K]  ->  qT_hi/qT_lo bf16 [K][DIM]  (transpose + hi/lo split)
__global__ void queue_split_kernel(const float* __restrict__ qd,
                                   uint16_t* __restrict__ qhi,
                                   uint16_t* __restrict__ qlo) {
    int q0 = blockIdx.x * 64;
    __shared__ float tile[DIM][65];
    for (int e = threadIdx.x; e < DIM * 64; e += 256) {
        int d = e >> 6, c = e & 63;
        tile[d][c] = qd[(int64_t)d * K + q0 + c];
    }
    __syncthreads();
    int qq = threadIdx.x >> 2;   // 0..63 (row within tile)
    int dg = threadIdx.x & 3;    // 0..3  (32 d each)
    uint16_t* gh = qhi + (int64_t)(q0 + qq) * DIM + dg * 32;
    uint16_t* gl = qlo + (int64_t)(q0 + qq) * DIM + dg * 32;
#pragma unroll
    for (int v = 0; v < 4; ++v) {
        uint32_t ph[4], pl[4];
#pragma unroll
        for (int p = 0; p < 4; ++p) {
            int d = dg * 32 + v * 8 + p * 2;
            uint16_t h0, l0, h1, l1;
            split2(tile[d][qq], h0, l0);
            split2(tile[d + 1][qq], h1, l1);
            ph[p] = (uint32_t)h0 | ((uint32_t)h1 << 16);
            pl[p] = (uint32_t)l0 | ((uint32_t)l1 << 16);
        }
        *(uint4*)(gh + v * 8) = make_uint4(ph[0], ph[1], ph[2], ph[3]);
        *(uint4*)(gl + v * 8) = make_uint4(pl[0], pl[1], pl[2], pl[3]);
    }
}

// ---------------------------------------------------------------------------
// Fused: gather d_q at match (normalized), emit transposed bf16 hi/lo
// d_qgT [b][z][DIM], and pos_d output (d_k norm fused).
__global__ void gather_prep_kernel(const float* __restrict__ d_q,
                                   const float* __restrict__ d_k,
                                   const float* __restrict__ rn_dq,
                                   const int* __restrict__ match,
                                   uint16_t* __restrict__ ghi,
                                   uint16_t* __restrict__ glo,
                                   float* __restrict__ out) {
    int b = blockIdx.y, z0 = blockIdx.x * 64;
    int zl = threadIdx.x & 63, dg = threadIdx.x >> 6;  // dg 0..3
    __shared__ float tile[DIM][65];
    __shared__ float redd[4][64], redn[4][64];
    __shared__ int   sm[64];
    __shared__ float ssc[64];
    if (threadIdx.x < 64) {
        int m = match[b * S + z0 + threadIdx.x];
        sm[threadIdx.x] = m;
        ssc[threadIdx.x] = rn_dq[b * S + m];
    }
    __syncthreads();
    int m = sm[zl];
    float sc = ssc[zl];
    const float* dqb = d_q + (int64_t)b * DIM * S;
    const float* dkb = d_k + (int64_t)b * DIM * S + z0;
    float dot = 0.0f, nk = 0.0f;
    for (int i = 0; i < 32; ++i) {
        int d = dg * 32 + i;
        float val = dqb[(int64_t)d * S + m] * sc;
        float kv  = dkb[(int64_t)d * S + zl];
        tile[d][zl] = val;
        dot = fmaf(kv, val, dot);
        nk  = fmaf(kv, kv, nk);
    }
    redd[dg][zl] = dot;
    redn[dg][zl] = nk;
    __syncthreads();
    if (dg == 0) {
        float D  = redd[0][zl] + redd[1][zl] + redd[2][zl] + redd[3][zl];
        float Nk = redn[0][zl] + redn[1][zl] + redn[2][zl] + redn[3][zl];
        out[OD_OFF + (int64_t)b * (K + 1) * S + z0 + zl] =
            D / fmaxf(sqrtf(Nk), EPSF) * INV_TAU;
    }
    // transposed split write: row z, 128 contiguous d
    int zz = threadIdx.x >> 2;   // 0..63
    int dg2 = threadIdx.x & 3;   // 0..3
    uint16_t* gh = ghi + ((int64_t)b * S + z0 + zz) * DIM + dg2 * 32;
    uint16_t* gl = glo + ((int64_t)b * S + z0 + zz) * DIM + dg2 * 32;
#pragma unroll
    for (int v = 0; v < 4; ++v) {
        uint32_t ph[4], pl[4];
#pragma unroll
        for (int p = 0; p < 4; ++p) {
            int d = dg2 * 32 + v * 8 + p * 2;
            uint16_t h0, l0, h1, l1;
            split2(tile[d][zz], h0, l0);
            split2(tile[d + 1][zz], h1, l1);
            ph[p] = (uint32_t)h0 | ((uint32_t)h1 << 16);
            pl[p] = (uint32_t)l0 | ((uint32_t)l1 << 16);
        }
        *(uint4*)(gh + v * 8) = make_uint4(ph[0], ph[1], ph[2], ph[3]);
        *(uint4*)(gl + v * 8) = make_uint4(pl[0], pl[1], pl[2], pl[3]);
    }
}

// ---------------------------------------------------------------------------
// neg_d via MFMA, bf16 hi/lo 3-pass split (AhBh + AhBl + AlBh), fp32 acc.
// C[q,z] = sum_d qT[q][d] * gT[b][z][d].
// Schedule (round-3 fix): XCD n (= d_id&7) owns the contiguous q-tile range
// [n*16, n*16+16) — its 1 MB q-slice stays L2-resident for the whole kernel.
// Inner order sweeps (z-tile, b) panels OUTER, the XCD's 16 q-tiles INNER,
// so each 64 KB z-panel is fetched once per XCD (total fetch ~5.2 MB/XCD),
// and same-row z-neighbor tiles are written close in time (edge-merge in L2).
// Epilogue: per-wave LDS transpose -> float4 writes (256B/row, no RMW).
__global__ void neg_d_mfma_kernel(const uint16_t* __restrict__ qhi,
                                  const uint16_t* __restrict__ qlo,
                                  const uint16_t* __restrict__ ghi,
                                  const uint16_t* __restrict__ glo,
                                  float* __restrict__ out) {
    int d_id = blockIdx.x;
    int xcd  = d_id & 7;
    int w    = d_id >> 3;              // per-XCD work index [0,1024)
    int x    = xcd * 16 + (w & 15);    // q-tile [0,128), 16-tile chunk per XCD
    int y    = (w >> 4) & 7;           // z-tile [0,8)
    int b    = w >> 7;                 // batch [0,8)

    int q0 = x * 128;
    int z0 = y * 128;
    int wave = threadIdx.x >> 6, lane = threadIdx.x & 63;
    int wq = q0 + (wave >> 1) * 64;      // wave's q origin
    int wz = z0 + (wave & 1) * 64;       // wave's z origin
    int r  = lane & 15;                  // A row / B col within 16
    int kd = (lane >> 4) * 8;            // k(d) offset within 32-chunk

    f32x4 acc[4][4];
    const f32x4 z4 = {0.0f, 0.0f, 0.0f, 0.0f};
#pragma unroll
    for (int i = 0; i < 4; ++i)
#pragma unroll
        for (int j = 0; j < 4; ++j) acc[i][j] = z4;

    const int64_t gbase = (int64_t)b * S;
#pragma unroll
    for (int ds = 0; ds < 4; ++ds) {
        int doff = ds * 32 + kd;
        s16x8 ah[4], al[4], bh[4], bl[4];
#pragma unroll
        for (int i = 0; i < 4; ++i) {
            int64_t arow = (int64_t)(wq + i * 16 + r) * DIM + doff;
            ah[i] = *(const s16x8*)(qhi + arow);
            al[i] = *(const s16x8*)(qlo + arow);
            int64_t brow = (gbase + wz + i * 16 + r) * DIM + doff;
            bh[i] = *(const s16x8*)(ghi + brow);
            bl[i] = *(const s16x8*)(glo + brow);
        }
        // pass 1: hi*hi
#pragma unroll
        for (int i = 0; i < 4; ++i)
#pragma unroll
            for (int j = 0; j < 4; ++j)
                acc[i][j] = __builtin_amdgcn_mfma_f32_16x16x32_bf16(ah[i], bh[j], acc[i][j], 0, 0, 0);
        // pass 2: hi*lo
#pragma unroll
        for (int i = 0; i < 4; ++i)
#pragma unroll
            for (int j = 0; j < 4; ++j)
                acc[i][j] = __builtin_amdgcn_mfma_f32_16x16x32_bf16(ah[i], bl[j], acc[i][j], 0, 0, 0);
        // pass 3: lo*hi
#pragma unroll
        for (int i = 0; i < 4; ++i)
#pragma unroll
            for (int j = 0; j < 4; ++j)
                acc[i][j] = __builtin_amdgcn_mfma_f32_16x16x32_bf16(al[i], bh[j], acc[i][j], 0, 0, 0);
    }

    // Epilogue: per-wave LDS transpose so global writes are float4 rows.
    // C/D layout (m89-verified): col = lane&15, row = (lane>>4)*4 + reg.
    __shared__ __align__(16) float st[4][16][68];
    int col = lane & 15;
    int rb  = (lane >> 4) * 4;
    int rr  = lane >> 4;           // read-phase row group 0..3
    int zc  = (lane & 15) * 4;     // read-phase z offset (float4)
#pragma unroll
    for (int i = 0; i < 4; ++i) {
#pragma unroll
        for (int j = 0; j < 4; ++j)
#pragma unroll
            for (int reg = 0; reg < 4; ++reg)
                st[wave][rb + reg][j * 16 + col] = acc[i][j][reg];
        __syncthreads();
#pragma unroll
        for (int pass = 0; pass < 4; ++pass) {
            int row = pass * 4 + rr;
            float4 v = *(const float4*)&st[wave][row][zc];
            v.x *= INV_TAU; v.y *= INV_TAU; v.z *= INV_TAU; v.w *= INV_TAU;
            int q = wq + i * 16 + row;
            *(float4*)&out[OD_OFF + ((int64_t)b * (K + 1) + 1 + q) * S + wz + zc] = v;
        }
        __syncthreads();
    }
}

// ---------------------------------------------------------------------------
extern "C" void kernel_launch(void* const* d_in, const int* in_sizes, int n_in,
                              void* d_out, int out_size, void* d_ws, size_t ws_size,
                              hipStream_t stream) {
    const float* g_q     = (const float*)d_in[0];
    const float* g_k     = (const float*)d_in[1];
    const float* d_q     = (const float*)d_in[2];
    const float* d_k     = (const float*)d_in[3];
    const float* feat_q  = (const float*)d_in[4];
    const float* feat_k  = (const float*)d_in[5];
    const float* queue_g = (const float*)d_in[6];
    const float* queue_d = (const float*)d_in[7];
    float* out = (float*)d_out;

    // Workspace carve: ~0.4 MB f32 scratch + 12.6 MB bf16 hi/lo operands
    float* ws    = (float*)d_ws;
    float* g_qn  = ws;               // 1024
    float* g_kn  = g_qn + 1024;      // 1024
    float* rn_fq = g_kn + 1024;      // 8192
    float* rn_fk = rn_fq + B * S;    // 8192
    float* rn_dq = rn_fk + B * S;    // 8192
    float* pmax  = rn_dq + B * S;    // 4*8192
    int*   pidx  = (int*)(pmax + 4 * B * S);  // 4*8192
    int*   match = pidx + 4 * B * S;          // 8192
    uint16_t* qhi = (uint16_t*)(match + B * S);   // [K][DIM] bf16
    uint16_t* qlo = qhi + (size_t)K * DIM;        // [K][DIM] bf16
    uint16_t* ghi = qlo + (size_t)K * DIM;        // [B][S][DIM] bf16
    uint16_t* glo = ghi + (size_t)B * S * DIM;    // [B][S][DIM] bf16

    zero_targets_kernel<<<(B * S + 255) / 256, 256, 0, stream>>>(out);
    g_norm_kernel<<<B, DIM, 0, stream>>>(g_q, g_k, g_qn, g_kn, out);
    neg_g_kernel<<<K / 256, 256, 0, stream>>>(g_qn, queue_g, out);
    queue_split_kernel<<<K / 64, 256, 0, stream>>>(queue_d, qhi, qlo);
    invnorm_kernel<CF><<<dim3(S / 64, B), 256, 0, stream>>>(feat_q, rn_fq);
    invnorm_kernel<CF><<<dim3(S / 64, B), 256, 0, stream>>>(feat_k, rn_fk);
    invnorm_kernel<DIM><<<dim3(S / 64, B), 256, 0, stream>>>(d_q, rn_dq);
    cos_argmax_kernel<<<dim3(S / 64, 4, B), 256, 0, stream>>>(feat_k, feat_q, rn_fk, rn_fq, pmax, pidx);
    argmax_merge_kernel<<<(B * S + 255) / 256, 256, 0, stream>>>(pmax, pidx, match);
    gather_prep_kernel<<<dim3(S / 64, B), 256, 0, stream>>>(d_q, d_k, rn_dq, match, ghi, glo, out);
    neg_d_mfma_kernel<<<8192, 256, 0, stream>>>(qhi, qlo, ghi, glo, out);
}

// Round 4
// 1189.329 us; speedup vs baseline: 1.2034x; 1.1387x over previous
//
#include <hip/hip_runtime.h>
#include <math.h>
#include <stdint.h>

// Problem constants
constexpr int B   = 8;
constexpr int DIM = 128;
constexpr int S   = 1024;
constexpr int CF  = 512;
constexpr int K   = 16384;
constexpr float INV_TAU = 5.0f;    // 1/0.2
constexpr float EPSF    = 1e-12f;

// Output layout (flat, in return order): output_g [B,1+K], target_g [B],
// output_d [B,1+K,S], target_d [B,S]
constexpr int64_t OG_OFF = 0;
constexpr int64_t TG_OFF = (int64_t)B * (K + 1);                 // 131080
constexpr int64_t OD_OFF = TG_OFF + B;                           // 131088
constexpr int64_t TD_OFF = OD_OFF + (int64_t)B * (K + 1) * S;    // 134357008

typedef __attribute__((ext_vector_type(8))) short s16x8;   // 8 bf16 (4 VGPRs)
typedef __attribute__((ext_vector_type(4))) float f32x4;   // MFMA accumulator

// Split fp32 into bf16 hi + bf16 lo (truncation; combined repr err ~2^-14 rel)
__device__ inline void split2(float x, uint16_t& h, uint16_t& l) {
    uint32_t bx = __float_as_uint(x);
    h = (uint16_t)(bx >> 16);
    float r = x - __uint_as_float(bx & 0xFFFF0000u);
    l = (uint16_t)(__float_as_uint(r) >> 16);
}

// ---------------------------------------------------------------------------
// Zero the int32 target outputs (bit pattern 0 is valid as both f32 and i32)
__global__ void zero_targets_kernel(float* out) {
    int t = blockIdx.x * 256 + threadIdx.x;
    if (t < B) out[TG_OFF + t] = 0.0f;
    if (t < B * S) out[TD_OFF + t] = 0.0f;
}

// ---------------------------------------------------------------------------
// Normalize g_q, g_k (axis=1, D=128); emit g_qn, g_kn and pos_g logits.
__global__ void g_norm_kernel(const float* __restrict__ g_q,
                              const float* __restrict__ g_k,
                              float* __restrict__ g_qn,
                              float* __restrict__ g_kn,
                              float* __restrict__ out) {
    int b = blockIdx.x;
    int d = threadIdx.x;  // 0..127
    float q = g_q[b * DIM + d];
    float k = g_k[b * DIM + d];
    float sq = q * q, sk = k * k;
#pragma unroll
    for (int off = 32; off > 0; off >>= 1) {
        sq += __shfl_down(sq, off, 64);
        sk += __shfl_down(sk, off, 64);
    }
    __shared__ float red[4];
    int w = d >> 6;
    if ((d & 63) == 0) { red[w] = sq; red[2 + w] = sk; }
    __syncthreads();
    float invq = 1.0f / fmaxf(sqrtf(red[0] + red[1]), EPSF);
    float invk = 1.0f / fmaxf(sqrtf(red[2] + red[3]), EPSF);
    float qn = q * invq, kn = k * invk;
    g_qn[b * DIM + d] = qn;
    g_kn[b * DIM + d] = kn;
    float p = qn * kn;
#pragma unroll
    for (int off = 32; off > 0; off >>= 1) p += __shfl_down(p, off, 64);
    __shared__ float red2[2];
    if ((d & 63) == 0) red2[w] = p;
    __syncthreads();
    if (d == 0) out[OG_OFF + (int64_t)b * (K + 1)] = (red2[0] + red2[1]) * INV_TAU;
}

// ---------------------------------------------------------------------------
// neg_g: out[b, 1+k] = (g_qn[b,:] . queue_g[:,k]) / TAU.
__global__ void neg_g_kernel(const float* __restrict__ g_qn,
                             const float* __restrict__ queue_g,
                             float* __restrict__ out) {
    __shared__ float gq[B * DIM];
    int t = threadIdx.x;
    for (int i = t; i < B * DIM; i += 256) gq[i] = g_qn[i];
    __syncthreads();
    int k = blockIdx.x * 256 + t;
    float acc[B] = {0, 0, 0, 0, 0, 0, 0, 0};
    for (int d = 0; d < DIM; ++d) {
        float v = queue_g[(int64_t)d * K + k];
#pragma unroll
        for (int b = 0; b < B; ++b) acc[b] = fmaf(gq[b * DIM + d], v, acc[b]);
    }
#pragma unroll
    for (int b = 0; b < B; ++b)
        out[OG_OFF + (int64_t)b * (K + 1) + 1 + k] = acc[b] * INV_TAU;
}

// ---------------------------------------------------------------------------
// Inverse L2 norms along the channel axis of x[B,ROWS,S] -> rn[B,S].
template <int ROWS>
__global__ void invnorm_kernel(const float* __restrict__ x, float* __restrict__ rn) {
    int b = blockIdx.y;
    int s = blockIdx.x * 64 + (threadIdx.x & 63);
    int g = threadIdx.x >> 6;
    const float* base = x + (int64_t)b * ROWS * S + s;
    float acc = 0.0f;
    for (int r = g; r < ROWS; r += 4) {
        float v = base[(int64_t)r * S];
        acc = fmaf(v, v, acc);
    }
    __shared__ float red[256];
    red[threadIdx.x] = acc;
    __syncthreads();
    if (g == 0) {
        int sl = threadIdx.x;
        float tot = red[sl] + red[64 + sl] + red[128 + sl] + red[192 + sl];
        rn[b * S + s] = 1.0f / fmaxf(sqrtf(tot), EPSF);
    }
}

// ---------------------------------------------------------------------------
// cosine argmax (unchanged this round; stays f32 — bf16 split risks flipping
// near-tie argmaxes, which would change gathered logits by O(1))
constexpr int CC = 32;
__global__ void cos_argmax_kernel(const float* __restrict__ f_k,
                                  const float* __restrict__ f_q,
                                  const float* __restrict__ rn_fk,
                                  const float* __restrict__ rn_fq,
                                  float* __restrict__ pmax,
                                  int* __restrict__ pidx) {
    int jt = blockIdx.x, ic = blockIdx.y, b = blockIdx.z;
    int j0 = jt * 64;
    int tx = threadIdx.x & 15, ty = threadIdx.x >> 4;
    __shared__ __align__(16) float sk[CC][68];
    __shared__ __align__(16) float sq[CC][68];
    const float* fkb = f_k + (int64_t)b * CF * S;
    const float* fqb = f_q + (int64_t)b * CF * S;

    float bestv[4];
    int besti[4];
#pragma unroll
    for (int jj = 0; jj < 4; ++jj) { bestv[jj] = -INFINITY; besti[jj] = 0; }
    float rq[4];
#pragma unroll
    for (int jj = 0; jj < 4; ++jj) rq[jj] = rn_fq[b * S + j0 + ty * 4 + jj];

    for (int it = 0; it < 4; ++it) {
        int i_base = ic * 256 + it * 64;
        float acc[4][4] = {};
        for (int c0 = 0; c0 < CF; c0 += CC) {
            for (int e = threadIdx.x; e < CC * 64; e += 256) {
                int r = e >> 6, col = e & 63;
                sk[r][col] = fkb[(int64_t)(c0 + r) * S + i_base + col];
                sq[r][col] = fqb[(int64_t)(c0 + r) * S + j0 + col];
            }
            __syncthreads();
#pragma unroll
            for (int r = 0; r < CC; ++r) {
                float4 av4 = *(const float4*)&sk[r][tx * 4];
                float4 bv4 = *(const float4*)&sq[r][ty * 4];
                float a_[4] = {av4.x, av4.y, av4.z, av4.w};
                float b_[4] = {bv4.x, bv4.y, bv4.z, bv4.w};
#pragma unroll
                for (int ii = 0; ii < 4; ++ii)
#pragma unroll
                    for (int jj = 0; jj < 4; ++jj)
                        acc[ii][jj] = fmaf(a_[ii], b_[jj], acc[ii][jj]);
            }
            __syncthreads();
        }
        float rk[4];
#pragma unroll
        for (int ii = 0; ii < 4; ++ii) rk[ii] = rn_fk[b * S + i_base + tx * 4 + ii];
#pragma unroll
        for (int jj = 0; jj < 4; ++jj)
#pragma unroll
            for (int ii = 0; ii < 4; ++ii) {
                float v = acc[ii][jj] * rk[ii] * rq[jj];
                if (v > bestv[jj]) { bestv[jj] = v; besti[jj] = i_base + tx * 4 + ii; }
            }
    }
#pragma unroll
    for (int jj = 0; jj < 4; ++jj) {
        float v = bestv[jj];
        int idx = besti[jj];
#pragma unroll
        for (int off = 8; off > 0; off >>= 1) {
            float ov = __shfl_down(v, off, 16);
            int oi = __shfl_down(idx, off, 16);
            if (ov > v || (ov == v && oi < idx)) { v = ov; idx = oi; }
        }
        if (tx == 0) {
            int j = j0 + ty * 4 + jj;
            pmax[(int64_t)(ic * B + b) * S + j] = v;
            pidx[(int64_t)(ic * B + b) * S + j] = idx;
        }
    }
}

__global__ void argmax_merge_kernel(const float* __restrict__ pmax,
                                    const int* __restrict__ pidx,
                                    int* __restrict__ match) {
    int t = blockIdx.x * 256 + threadIdx.x;
    if (t >= B * S) return;
    int b = t / S, s = t % S;
    float bv = -INFINITY;
    int bi = 0;
    for (int ic = 0; ic < 4; ++ic) {
        float v = pmax[(int64_t)(ic * B + b) * S + s];
        int i = pidx[(int64_t)(ic * B + b) * S + s];
        if (v > bv || (v == bv && i < bi)) { bv = v; bi = i; }
    }
    match[t] = bi;
}

// ---------------------------------------------------------------------------
// queue_d f32 [DIM][K]  ->  qT_hi/qT_lo bf16 [K][DIM]  (transpose + hi/lo split)
__global__ void queue_split_kernel(const float* __restrict__ qd,
                                   uint16_t* __restrict__ qhi,
                                   uint16_t* __restrict__ qlo) {
    int q0 = blockIdx.x * 64;
    __shared__ float tile[DIM][65];
    for (int e = threadIdx.x; e < DIM * 64; e += 256) {
        int d = e >> 6, c = e & 63;
        tile[d][c] = qd[(int64_t)d * K + q0 + c];
    }
    __syncthreads();
    int qq = threadIdx.x >> 2;   // 0..63 (row within tile)
    int dg = threadIdx.x & 3;    // 0..3  (32 d each)
    uint16_t* gh = qhi + (int64_t)(q0 + qq) * DIM + dg * 32;
    uint16_t* gl = qlo + (int64_t)(q0 + qq) * DIM + dg * 32;
#pragma unroll
    for (int v = 0; v < 4; ++v) {
        uint32_t ph[4], pl[4];
#pragma unroll
        for (int p = 0; p < 4; ++p) {
            int d = dg * 32 + v * 8 + p * 2;
            uint16_t h0, l0, h1, l1;
            split2(tile[d][qq], h0, l0);
            split2(tile[d + 1][qq], h1, l1);
            ph[p] = (uint32_t)h0 | ((uint32_t)h1 << 16);
            pl[p] = (uint32_t)l0 | ((uint32_t)l1 << 16);
        }
        *(uint4*)(gh + v * 8) = make_uint4(ph[0], ph[1], ph[2], ph[3]);
        *(uint4*)(gl + v * 8) = make_uint4(pl[0], pl[1], pl[2], pl[3]);
    }
}

// ---------------------------------------------------------------------------
// Fused: gather d_q at match (normalized), emit transposed bf16 hi/lo
// d_qgT [b][z][DIM], and pos_d output (d_k norm fused).
__global__ void gather_prep_kernel(const float* __restrict__ d_q,
                                   const float* __restrict__ d_k,
                                   const float* __restrict__ rn_dq,
                                   const int* __restrict__ match,
                                   uint16_t* __restrict__ ghi,
                                   uint16_t* __restrict__ glo,
                                   float* __restrict__ out) {
    int b = blockIdx.y, z0 = blockIdx.x * 64;
    int zl = threadIdx.x & 63, dg = threadIdx.x >> 6;  // dg 0..3
    __shared__ float tile[DIM][65];
    __shared__ float redd[4][64], redn[4][64];
    __shared__ int   sm[64];
    __shared__ float ssc[64];
    if (threadIdx.x < 64) {
        int m = match[b * S + z0 + threadIdx.x];
        sm[threadIdx.x] = m;
        ssc[threadIdx.x] = rn_dq[b * S + m];
    }
    __syncthreads();
    int m = sm[zl];
    float sc = ssc[zl];
    const float* dqb = d_q + (int64_t)b * DIM * S;
    const float* dkb = d_k + (int64_t)b * DIM * S + z0;
    float dot = 0.0f, nk = 0.0f;
    for (int i = 0; i < 32; ++i) {
        int d = dg * 32 + i;
        float val = dqb[(int64_t)d * S + m] * sc;
        float kv  = dkb[(int64_t)d * S + zl];
        tile[d][zl] = val;
        dot = fmaf(kv, val, dot);
        nk  = fmaf(kv, kv, nk);
    }
    redd[dg][zl] = dot;
    redn[dg][zl] = nk;
    __syncthreads();
    if (dg == 0) {
        float D  = redd[0][zl] + redd[1][zl] + redd[2][zl] + redd[3][zl];
        float Nk = redn[0][zl] + redn[1][zl] + redn[2][zl] + redn[3][zl];
        out[OD_OFF + (int64_t)b * (K + 1) * S + z0 + zl] =
            D / fmaxf(sqrtf(Nk), EPSF) * INV_TAU;
    }
    // transposed split write: row z, 128 contiguous d
    int zz = threadIdx.x >> 2;   // 0..63
    int dg2 = threadIdx.x & 3;   // 0..3
    uint16_t* gh = ghi + ((int64_t)b * S + z0 + zz) * DIM + dg2 * 32;
    uint16_t* gl = glo + ((int64_t)b * S + z0 + zz) * DIM + dg2 * 32;
#pragma unroll
    for (int v = 0; v < 4; ++v) {
        uint32_t ph[4], pl[4];
#pragma unroll
        for (int p = 0; p < 4; ++p) {
            int d = dg2 * 32 + v * 8 + p * 2;
            uint16_t h0, l0, h1, l1;
            split2(tile[d][zz], h0, l0);
            split2(tile[d + 1][zz], h1, l1);
            ph[p] = (uint32_t)h0 | ((uint32_t)h1 << 16);
            pl[p] = (uint32_t)l0 | ((uint32_t)l1 << 16);
        }
        *(uint4*)(gh + v * 8) = make_uint4(ph[0], ph[1], ph[2], ph[3]);
        *(uint4*)(gl + v * 8) = make_uint4(pl[0], pl[1], pl[2], pl[3]);
    }
}

// ---------------------------------------------------------------------------
// neg_d via MFMA, bf16 hi/lo 3-pass split (AhBh + AhBl + AlBh), fp32 acc.
// C[q,z] = sum_d qT[q][d] * gT[b][z][d].
// Schedule: XCD n (= d_id&7) owns q-tiles [n*16, n*16+16) — its 2 MB q-slice
// stays L2-resident; (z,b) panels outer, q inner (operand fetch ~90 MB total,
// verified round 3). Epilogue: direct per-lane NONTEMPORAL dword stores.
// The od region is write-once/never-read: nt (no-allocate) stores skip L2
// write-allocate RMW churn (round-3 counters: +537 MB fetch, 2.6x write amp).
// Each 16-lane chunk is a 64-B sector-aligned span (OD row phase is 64 mod
// 128), so nt stores need no read-modify-write at any level.
__global__ void neg_d_mfma_kernel(const uint16_t* __restrict__ qhi,
                                  const uint16_t* __restrict__ qlo,
                                  const uint16_t* __restrict__ ghi,
                                  const uint16_t* __restrict__ glo,
                                  float* __restrict__ out) {
    int d_id = blockIdx.x;
    int xcd  = d_id & 7;
    int w    = d_id >> 3;              // per-XCD work index [0,1024)
    int x    = xcd * 16 + (w & 15);    // q-tile [0,128), 16-tile chunk per XCD
    int y    = (w >> 4) & 7;           // z-tile [0,8)
    int b    = w >> 7;                 // batch [0,8)

    int q0 = x * 128;
    int z0 = y * 128;
    int wave = threadIdx.x >> 6, lane = threadIdx.x & 63;
    int wq = q0 + (wave >> 1) * 64;      // wave's q origin
    int wz = z0 + (wave & 1) * 64;       // wave's z origin
    int r  = lane & 15;                  // A row / B col within 16
    int kd = (lane >> 4) * 8;            // k(d) offset within 32-chunk

    f32x4 acc[4][4];
    const f32x4 z4 = {0.0f, 0.0f, 0.0f, 0.0f};
#pragma unroll
    for (int i = 0; i < 4; ++i)
#pragma unroll
        for (int j = 0; j < 4; ++j) acc[i][j] = z4;

    const int64_t gbase = (int64_t)b * S;
#pragma unroll
    for (int ds = 0; ds < 4; ++ds) {
        int doff = ds * 32 + kd;
        s16x8 ah[4], al[4], bh[4], bl[4];
#pragma unroll
        for (int i = 0; i < 4; ++i) {
            int64_t arow = (int64_t)(wq + i * 16 + r) * DIM + doff;
            ah[i] = *(const s16x8*)(qhi + arow);
            al[i] = *(const s16x8*)(qlo + arow);
            int64_t brow = (gbase + wz + i * 16 + r) * DIM + doff;
            bh[i] = *(const s16x8*)(ghi + brow);
            bl[i] = *(const s16x8*)(glo + brow);
        }
        // pass 1: hi*hi
#pragma unroll
        for (int i = 0; i < 4; ++i)
#pragma unroll
            for (int j = 0; j < 4; ++j)
                acc[i][j] = __builtin_amdgcn_mfma_f32_16x16x32_bf16(ah[i], bh[j], acc[i][j], 0, 0, 0);
        // pass 2: hi*lo
#pragma unroll
        for (int i = 0; i < 4; ++i)
#pragma unroll
            for (int j = 0; j < 4; ++j)
                acc[i][j] = __builtin_amdgcn_mfma_f32_16x16x32_bf16(ah[i], bl[j], acc[i][j], 0, 0, 0);
        // pass 3: lo*hi
#pragma unroll
        for (int i = 0; i < 4; ++i)
#pragma unroll
            for (int j = 0; j < 4; ++j)
                acc[i][j] = __builtin_amdgcn_mfma_f32_16x16x32_bf16(al[i], bh[j], acc[i][j], 0, 0, 0);
    }

    // Epilogue: direct nontemporal stores.
    // C/D layout (m89-verified): col = lane&15, row = (lane>>4)*4 + reg.
    int col = lane & 15;
    int rb  = (lane >> 4) * 4;
#pragma unroll
    for (int i = 0; i < 4; ++i) {
        int q = wq + i * 16 + rb;
#pragma unroll
        for (int j = 0; j < 4; ++j) {
            int z = wz + j * 16 + col;
            float* o = out + OD_OFF + ((int64_t)b * (K + 1) + 1 + q) * S + z;
#pragma unroll
            for (int reg = 0; reg < 4; ++reg)
                __builtin_nontemporal_store(acc[i][j][reg] * INV_TAU,
                                            o + (int64_t)reg * S);
        }
    }
}

// ---------------------------------------------------------------------------
extern "C" void kernel_launch(void* const* d_in, const int* in_sizes, int n_in,
                              void* d_out, int out_size, void* d_ws, size_t ws_size,
                              hipStream_t stream) {
    const float* g_q     = (const float*)d_in[0];
    const float* g_k     = (const float*)d_in[1];
    const float* d_q     = (const float*)d_in[2];
    const float* d_k     = (const float*)d_in[3];
    const float* feat_q  = (const float*)d_in[4];
    const float* feat_k  = (const float*)d_in[5];
    const float* queue_g = (const float*)d_in[6];
    const float* queue_d = (const float*)d_in[7];
    float* out = (float*)d_out;

    // Workspace carve: ~0.4 MB f32 scratch + 12.6 MB bf16 hi/lo operands
    float* ws    = (float*)d_ws;
    float* g_qn  = ws;               // 1024
    float* g_kn  = g_qn + 1024;      // 1024
    float* rn_fq = g_kn + 1024;      // 8192
    float* rn_fk = rn_fq + B * S;    // 8192
    float* rn_dq = rn_fk + B * S;    // 8192
    float* pmax  = rn_dq + B * S;    // 4*8192
    int*   pidx  = (int*)(pmax + 4 * B * S);  // 4*8192
    int*   match = pidx + 4 * B * S;          // 8192
    uint16_t* qhi = (uint16_t*)(match + B * S);   // [K][DIM] bf16
    uint16_t* qlo = qhi + (size_t)K * DIM;        // [K][DIM] bf16
    uint16_t* ghi = qlo + (size_t)K * DIM;        // [B][S][DIM] bf16
    uint16_t* glo = ghi + (size_t)B * S * DIM;    // [B][S][DIM] bf16

    zero_targets_kernel<<<(B * S + 255) / 256, 256, 0, stream>>>(out);
    g_norm_kernel<<<B, DIM, 0, stream>>>(g_q, g_k, g_qn, g_kn, out);
    neg_g_kernel<<<K / 256, 256, 0, stream>>>(g_qn, queue_g, out);
    queue_split_kernel<<<K / 64, 256, 0, stream>>>(queue_d, qhi, qlo);
    invnorm_kernel<CF><<<dim3(S / 64, B), 256, 0, stream>>>(feat_q, rn_fq);
    invnorm_kernel<CF><<<dim3(S / 64, B), 256, 0, stream>>>(feat_k, rn_fk);
    invnorm_kernel<DIM><<<dim3(S / 64, B), 256, 0, stream>>>(d_q, rn_dq);
    cos_argmax_kernel<<<dim3(S / 64, 4, B), 256, 0, stream>>>(feat_k, feat_q, rn_fk, rn_fq, pmax, pidx);
    argmax_merge_kernel<<<(B * S + 255) / 256, 256, 0, stream>>>(pmax, pidx, match);
    gather_prep_kernel<<<dim3(S / 64, B), 256, 0, stream>>>(d_q, d_k, rn_dq, match, ghi, glo, out);
    neg_d_mfma_kernel<<<8192, 256, 0, stream>>>(qhi, qlo, ghi, glo, out);
}